// Round 16
// baseline (56.967 us; speedup 1.0000x reference)
//
#include <hip/hip_runtime.h>
#include <hip/hip_bf16.h>

// B=8, Te=512, Td=128, D_ENC=D_DEC=512, ATT=256
//  prep      : A,B -> fragment-swizzled bf16 hi/lo planes
//  gemm_mfma : split-bf16 3-pass MFMA; epilogue stores Ew/Eu = exp2(2log2e*x)
//  scores_k  : S = sum_a V[a]*rcp(fmaf(Ew,Eu,1)), 2t x 4s micro-tile,
//              8-way a-split (13.8KB LDS, grid 2048 -> 100% occ-capable)
//  softctx   : p = softmax(-2S) over 8 partial planes; context + out_e

typedef __attribute__((ext_vector_type(8))) short bf16x8;
typedef __attribute__((ext_vector_type(4))) float f32x4;

__device__ inline void f32_to_bf16_pair(float x, short& h, short& l) {
    unsigned u = __builtin_bit_cast(unsigned, x);
    unsigned r = u + 0x7FFFu + ((u >> 16) & 1u);           // RNE
    h = (short)(r >> 16);
    float xh = __builtin_bit_cast(float, r & 0xFFFF0000u);
    float xl = x - xh;
    unsigned u2 = __builtin_bit_cast(unsigned, xl);
    unsigned r2 = u2 + 0x7FFFu + ((u2 >> 16) & 1u);
    l = (short)(r2 >> 16);
}

// ---------------------------------------------------------------------------
// Kernel 0: merged prep (r12-validated, unchanged).
// ---------------------------------------------------------------------------
__global__ __launch_bounds__(256) void prep(
    const float* __restrict__ W_h, const float* __restrict__ U_a,
    const float* __restrict__ values, const float* __restrict__ query,
    short* __restrict__ BHi, short* __restrict__ BLo,
    short* __restrict__ AHi, short* __restrict__ ALo)
{
    __shared__ float TW[64][65];
    __shared__ float TA[16][516];
    const int bid = blockIdx.x;
    const int tid = threadIdx.x;

    if (bid < 64) {
        const int mat = bid >> 5, nb = (bid >> 3) & 3, kb = bid & 7;
        const float* W = mat ? U_a : W_h;
        {
            const int krow = tid >> 2, cq = (tid & 3) * 16;
            const float* src = W + (size_t)(kb * 64 + krow) * 256 + nb * 64 + cq;
            #pragma unroll
            for (int q = 0; q < 4; ++q)
                *(float4*)&TW[krow][cq + q * 4] = *(const float4*)&src[q * 4];
        }
        __syncthreads();
        {
            const int f = tid >> 5;
            const int ngl = f >> 1, ksl = f & 1;
            const int l0 = (tid & 31) * 2;
            const int ngrp = nb * 4 + ngl;
            const int ksg = kb * 2 + ksl;
            const size_t base = (size_t)mat * 131072 + (size_t)(ngrp * 16 + ksg) * 512;
            #pragma unroll
            for (int li = 0; li < 2; ++li) {
                const int lane = l0 + li;
                const int lr = lane & 15, lg = lane >> 4;
                bf16x8 hv, lv;
                #pragma unroll
                for (int j = 0; j < 8; ++j) {
                    short h, l;
                    f32_to_bf16_pair(TW[ksl * 32 + lg * 8 + j][ngl * 16 + lr], h, l);
                    hv[j] = h; lv[j] = l;
                }
                *(bf16x8*)(BHi + base + lane * 8) = hv;
                *(bf16x8*)(BLo + base + lane * 8) = lv;
            }
        }
    } else {
        const int mg = bid - 64;
        const float* src = (mg < 256) ? values + (size_t)mg * 16 * 512
                                      : query + (size_t)(mg - 256) * 16 * 512;
        {
            const int row = tid >> 4, c0 = (tid & 15) * 4;
            #pragma unroll
            for (int i = 0; i < 8; ++i)
                *(float4*)&TA[row][c0 + i * 64] =
                    *(const float4*)&src[(size_t)row * 512 + c0 + i * 64];
        }
        __syncthreads();
        {
            const int ks = tid >> 4;
            const int l4 = (tid & 15) * 4;
            const size_t base = ((size_t)(mg * 16 + ks)) * 512;
            #pragma unroll
            for (int li = 0; li < 4; ++li) {
                const int lane = l4 + li;
                const int lr = lane & 15, lg = lane >> 4;
                bf16x8 hv, lv;
                #pragma unroll
                for (int j = 0; j < 8; ++j) {
                    short h, l;
                    f32_to_bf16_pair(TA[lr][ks * 32 + lg * 8 + j], h, l);
                    hv[j] = h; lv[j] = l;
                }
                *(bf16x8*)(AHi + base + lane * 8) = hv;
                *(bf16x8*)(ALo + base + lane * 8) = lv;
            }
        }
    }
}

// ---------------------------------------------------------------------------
// Kernel 1: MFMA split-bf16 GEMM (r12-validated, unchanged).
// ---------------------------------------------------------------------------
__global__ __launch_bounds__(128) void gemm_mfma(
    const short* __restrict__ AHi, const short* __restrict__ ALo,
    const short* __restrict__ BHi, const short* __restrict__ BLo,
    float* __restrict__ EwO, float* __restrict__ EuO)
{
    const int bid = blockIdx.x;
    const int mt = bid >> 2, nt = bid & 3;
    const int tid = threadIdx.x;
    const int w = tid >> 6, l = tid & 63;
    const int lr = l & 15, lg = l >> 4;

    float* C; int m0, mg, matoff;
    if (mt < 128) { C = EwO; m0 = mt * 32; mg = mt * 2 + w; matoff = 0; }
    else { C = EuO; m0 = (mt - 128) * 32; mg = 256 + (mt - 128) * 2 + w; matoff = 131072; }

    const short* ah_p = AHi + ((size_t)mg * 16) * 512 + l * 8;
    const short* al_p = ALo + ((size_t)mg * 16) * 512 + l * 8;
    const short* bh_p = BHi + matoff + ((size_t)(nt * 4) * 16) * 512 + l * 8;
    const short* bl_p = BLo + matoff + ((size_t)(nt * 4) * 16) * 512 + l * 8;

    f32x4 acc[4];
    #pragma unroll
    for (int nc = 0; nc < 4; ++nc) acc[nc] = (f32x4){0.f, 0.f, 0.f, 0.f};

    #pragma unroll 2
    for (int ks = 0; ks < 16; ++ks) {
        bf16x8 ah = *(const bf16x8*)(ah_p + (size_t)ks * 512);
        bf16x8 al = *(const bf16x8*)(al_p + (size_t)ks * 512);
        #pragma unroll
        for (int nc = 0; nc < 4; ++nc) {
            bf16x8 bh = *(const bf16x8*)(bh_p + ((size_t)(nc * 16 + ks)) * 512);
            bf16x8 bl = *(const bf16x8*)(bl_p + ((size_t)(nc * 16 + ks)) * 512);
            acc[nc] = __builtin_amdgcn_mfma_f32_16x16x32_bf16(ah, bh, acc[nc], 0, 0, 0);
            acc[nc] = __builtin_amdgcn_mfma_f32_16x16x32_bf16(al, bh, acc[nc], 0, 0, 0);
            acc[nc] = __builtin_amdgcn_mfma_f32_16x16x32_bf16(ah, bl, acc[nc], 0, 0, 0);
        }
    }

    const float SCL = 2.8853900817779268f;  // 2*log2(e)
    float* cp = C + (size_t)(m0 + w * 16 + lg * 4) * 256 + nt * 64 + lr;
    #pragma unroll
    for (int nc = 0; nc < 4; ++nc)
        #pragma unroll
        for (int r = 0; r < 4; ++r)
            cp[(size_t)r * 256 + nc * 16] = __builtin_amdgcn_exp2f(acc[nc][r] * SCL);
}

// ---------------------------------------------------------------------------
// Kernel 2: score partials, 2t x 4s micro-tile, 8-way a-split.
// Grid 2048 = 8b x 8ah x 4tt x 8st, 256 thr.  Block = 32t x 64s x 32a.
// LDS 13.8KB -> 8 blocks/CU (100% occ).  S = sum_a V[a]*rcp(fmaf(Ew,Eu,1)).
// ---------------------------------------------------------------------------
__global__ __launch_bounds__(256) void scores_k(
    const float* __restrict__ Ew, const float* __restrict__ Eu,
    const float* __restrict__ Va, float* __restrict__ scoresP)
{
    __shared__ float Ws[64][36];   // bank=(4r+c)%32: rows r,r+8 alias -> 2-way free
    __shared__ float Us[32][36];

    const int bid = blockIdx.x;
    const int b = bid & 7;               // XCD-pinned per batch
    const int rest = bid >> 3;           // 0..255
    const int ah = rest & 7;             // 8 a-tiles of 32
    const int tt = (rest >> 3) & 3;      // 4 t-tiles of 32
    const int st = rest >> 5;            // 8 s-tiles of 64
    const int t0 = tt * 32, s0 = st * 64, a0 = ah * 32;
    const int tid = threadIdx.x;

    {   // stage Ew (64s x 32a) and Eu (32t x 32a)
        const int r = tid >> 2, c8 = (tid & 3) * 8;
        const float* wsrc = Ew + (size_t)(b * 512 + s0 + r) * 256 + a0 + c8;
        *(float4*)&Ws[r][c8]     = *(const float4*)&wsrc[0];
        *(float4*)&Ws[r][c8 + 4] = *(const float4*)&wsrc[4];
        const int r8 = tid >> 3, c4 = (tid & 7) * 4;
        const float* usrc = Eu + (size_t)(b * 128 + t0 + r8) * 256 + a0 + c4;
        *(float4*)&Us[r8][c4] = *(const float4*)&usrc[0];
    }
    __syncthreads();

    const int tb = tid >> 4;             // t rows {tb, tb+16}
    const int ss = tid & 15;             // s rows {ss, ss+16, ss+32, ss+48}
    const float* Vp = Va + a0;

    float acc[2][4] = {};
    #pragma unroll
    for (int a = 0; a < 32; a += 4) {
        float4 u0 = *(const float4*)&Us[tb][a];
        float4 u1 = *(const float4*)&Us[tb + 16][a];
        float4 w0 = *(const float4*)&Ws[ss][a];
        float4 w1 = *(const float4*)&Ws[ss + 16][a];
        float4 w2 = *(const float4*)&Ws[ss + 32][a];
        float4 w3 = *(const float4*)&Ws[ss + 48][a];
        const float uv[2][4] = {{u0.x, u0.y, u0.z, u0.w}, {u1.x, u1.y, u1.z, u1.w}};
        const float wv[4][4] = {{w0.x, w0.y, w0.z, w0.w}, {w1.x, w1.y, w1.z, w1.w},
                                {w2.x, w2.y, w2.z, w2.w}, {w3.x, w3.y, w3.z, w3.w}};
        #pragma unroll
        for (int q = 0; q < 4; ++q) {
            const float vq = Vp[a + q];  // wave-uniform -> scalar load
            #pragma unroll
            for (int i = 0; i < 2; ++i)
                #pragma unroll
                for (int k = 0; k < 4; ++k) {
                    float rc = __builtin_amdgcn_rcpf(fmaf(wv[k][q], uv[i][q], 1.f));
                    acc[i][k] = fmaf(vq, rc, acc[i][k]);
                }
        }
    }

    float* sp = scoresP + (size_t)ah * 524288
              + (size_t)(b * 128 + t0 + tb) * 512 + s0 + ss;
    #pragma unroll
    for (int k = 0; k < 4; ++k) sp[k * 16] = acc[0][k];
    sp += (size_t)16 * 512;
    #pragma unroll
    for (int k = 0; k < 4; ++k) sp[k * 16] = acc[1][k];
}

// ---------------------------------------------------------------------------
// Kernel 3: combine 8 partial planes + softmax + context, 8t per block.
// Grid 512 = 8b x 16 tg(8t) x 4 eh, 256 thr.  p = softmax(-2*S).
// ---------------------------------------------------------------------------
__global__ __launch_bounds__(256) void softctx(
    const float* __restrict__ scoresP, const float* __restrict__ values,
    float* __restrict__ out_c, float* __restrict__ out_e)
{
    __shared__ float Ps[8][512];
    __shared__ float Part[7][8][128];

    const int bid = blockIdx.x;
    const int b = bid & 7;
    const int rest = bid >> 3;         // 0..63
    const int tg = rest & 15;
    const int eh = rest >> 4;          // 0..3
    const int t0 = tg * 8;
    const int tid = threadIdx.x;

    {   // softmax: row = tid>>5 (0..7), 32 lanes per row
        const int row = tid >> 5, lane = tid & 31;
        const float* sp = scoresP + (size_t)(b * 128 + t0 + row) * 512;
        float e[16]; float ssum = 0.f;
        #pragma unroll
        for (int k = 0; k < 16; ++k) {
            const int idx = k * 32 + lane;
            float s = 0.f;
            #pragma unroll
            for (int g = 0; g < 8; ++g)
                s += sp[(size_t)g * 524288 + idx];
            e[k] = __builtin_amdgcn_exp2f(s * -2.8853900817779268f);  // exp(-2S)
            ssum += e[k];
        }
        #pragma unroll
        for (int off = 16; off > 0; off >>= 1)      // stays within 32-lane group
            ssum += __shfl_xor(ssum, off);
        const float inv = 1.0f / ssum;
        float* erow = out_e + (size_t)(b * 128 + t0 + row) * 512;
        #pragma unroll
        for (int k = 0; k < 16; ++k) {
            float p = e[k] * inv;
            Ps[row][k * 32 + lane] = p;
            if (eh == 0) erow[k * 32 + lane] = p;
        }
    }
    __syncthreads();

    const int sh = tid >> 5;           // 0..7 s-split
    const int el = (tid & 31) * 4;     // 0..124
    const int e4 = eh * 128 + el;
    const int sb = sh * 64;
    const float* vb = values + (size_t)b * 262144;

    f32x4 a[8];
    #pragma unroll
    for (int r = 0; r < 8; ++r) a[r] = (f32x4){0.f, 0.f, 0.f, 0.f};

    #pragma unroll 2
    for (int s2 = 0; s2 < 64; s2 += 4) {
        float4 q[8];
        #pragma unroll
        for (int r = 0; r < 8; ++r)
            q[r] = *(const float4*)&Ps[r][sb + s2];
        #pragma unroll
        for (int j = 0; j < 4; ++j) {
            float4 v4 = *(const float4*)&vb[(size_t)(sb + s2 + j) * 512 + e4];
            #pragma unroll
            for (int r = 0; r < 8; ++r) {
                const float qv = (j == 0) ? q[r].x : (j == 1) ? q[r].y
                               : (j == 2) ? q[r].z : q[r].w;
                a[r][0] = fmaf(qv, v4.x, a[r][0]);
                a[r][1] = fmaf(qv, v4.y, a[r][1]);
                a[r][2] = fmaf(qv, v4.z, a[r][2]);
                a[r][3] = fmaf(qv, v4.w, a[r][3]);
            }
        }
    }

    if (sh) {
        #pragma unroll
        for (int r = 0; r < 8; ++r)
            *(f32x4*)&Part[sh - 1][r][el] = a[r];
    }
    __syncthreads();
    if (!sh) {
        #pragma unroll
        for (int r = 0; r < 8; ++r) {
            f32x4 accv = a[r];
            #pragma unroll
            for (int g = 0; g < 7; ++g) {
                float4 p4 = *(const float4*)&Part[g][r][el];
                accv[0] += p4.x; accv[1] += p4.y; accv[2] += p4.z; accv[3] += p4.w;
            }
            *(f32x4*)&out_c[(size_t)(b * 128 + t0 + r) * 512 + e4] = accv;
        }
    }
}

// ---------------------------------------------------------------------------
extern "C" void kernel_launch(void* const* d_in, const int* in_sizes, int n_in,
                              void* d_out, int out_size, void* d_ws, size_t ws_size,
                              hipStream_t stream) {
    const float* values = (const float*)d_in[0];  // [8,512,512]
    const float* query  = (const float*)d_in[1];  // [8,128,512]
    const float* W_h    = (const float*)d_in[2];  // [512,256]
    const float* U_a    = (const float*)d_in[3];  // [512,256]
    const float* V_a    = (const float*)d_in[4];  // [1,256]

    float* ws      = (float*)d_ws;
    float* Ew      = ws;                           // 4096*256 f32
    float* Eu      = ws + 1048576;                 // 1024*256 f32
    float* scoresP = ws + 1310720;                 // 8 * 524288 f32
    short* S       = (short*)(ws + 5505024);
    short* AHi     = S;                            // 5120*512 bf16
    short* ALo     = S + 2621440;
    short* BHi     = S + 5242880;                  // 2*256*512 bf16
    short* BLo     = S + 5505024;

    float* out_c = (float*)d_out;                  // [8,128,512]
    float* out_e = out_c + 8 * 128 * 512;          // [8,128,512]

    hipLaunchKernelGGL(prep, dim3(384), dim3(256), 0, stream,
                       W_h, U_a, values, query, BHi, BLo, AHi, ALo);
    hipLaunchKernelGGL(gemm_mfma, dim3(640), dim3(128), 0, stream,
                       AHi, ALo, BHi, BLo, Ew, Eu);
    hipLaunchKernelGGL(scores_k, dim3(2048), dim3(256), 0, stream,
                       Ew, Eu, V_a, scoresP);
    hipLaunchKernelGGL(softctx, dim3(512), dim3(256), 0, stream,
                       scoresP, values, out_c, out_e);
}

// Round 17
// 54.712 us; speedup vs baseline: 1.0412x; 1.0412x over previous
//
#include <hip/hip_runtime.h>
#include <hip/hip_bf16.h>

// B=8, Te=512, Td=128, D_ENC=D_DEC=512, ATT=256
//  prep      : A,B -> fragment-swizzled bf16 hi/lo planes
//  gemm_mfma : split-bf16 3-pass MFMA; epilogue stores Ew/Eu = exp2(2log2e*x)
//  scores_k  : S = sum_a V[a]*rcp(fmaf(Ew,Eu,1)), 2t x 4s micro-tile, 4-way a-split
//  softctx   : p = softmax(-2S); context + out_e  (8t blocks, e-split 8)

typedef __attribute__((ext_vector_type(8))) short bf16x8;
typedef __attribute__((ext_vector_type(4))) float f32x4;

__device__ inline void f32_to_bf16_pair(float x, short& h, short& l) {
    unsigned u = __builtin_bit_cast(unsigned, x);
    unsigned r = u + 0x7FFFu + ((u >> 16) & 1u);           // RNE
    h = (short)(r >> 16);
    float xh = __builtin_bit_cast(float, r & 0xFFFF0000u);
    float xl = x - xh;
    unsigned u2 = __builtin_bit_cast(unsigned, xl);
    unsigned r2 = u2 + 0x7FFFu + ((u2 >> 16) & 1u);
    l = (short)(r2 >> 16);
}

// ---------------------------------------------------------------------------
// Kernel 0: merged prep (r12-validated, unchanged).
// ---------------------------------------------------------------------------
__global__ __launch_bounds__(256) void prep(
    const float* __restrict__ W_h, const float* __restrict__ U_a,
    const float* __restrict__ values, const float* __restrict__ query,
    short* __restrict__ BHi, short* __restrict__ BLo,
    short* __restrict__ AHi, short* __restrict__ ALo)
{
    __shared__ float TW[64][65];
    __shared__ float TA[16][516];
    const int bid = blockIdx.x;
    const int tid = threadIdx.x;

    if (bid < 64) {
        const int mat = bid >> 5, nb = (bid >> 3) & 3, kb = bid & 7;
        const float* W = mat ? U_a : W_h;
        {
            const int krow = tid >> 2, cq = (tid & 3) * 16;
            const float* src = W + (size_t)(kb * 64 + krow) * 256 + nb * 64 + cq;
            #pragma unroll
            for (int q = 0; q < 4; ++q)
                *(float4*)&TW[krow][cq + q * 4] = *(const float4*)&src[q * 4];
        }
        __syncthreads();
        {
            const int f = tid >> 5;
            const int ngl = f >> 1, ksl = f & 1;
            const int l0 = (tid & 31) * 2;
            const int ngrp = nb * 4 + ngl;
            const int ksg = kb * 2 + ksl;
            const size_t base = (size_t)mat * 131072 + (size_t)(ngrp * 16 + ksg) * 512;
            #pragma unroll
            for (int li = 0; li < 2; ++li) {
                const int lane = l0 + li;
                const int lr = lane & 15, lg = lane >> 4;
                bf16x8 hv, lv;
                #pragma unroll
                for (int j = 0; j < 8; ++j) {
                    short h, l;
                    f32_to_bf16_pair(TW[ksl * 32 + lg * 8 + j][ngl * 16 + lr], h, l);
                    hv[j] = h; lv[j] = l;
                }
                *(bf16x8*)(BHi + base + lane * 8) = hv;
                *(bf16x8*)(BLo + base + lane * 8) = lv;
            }
        }
    } else {
        const int mg = bid - 64;
        const float* src = (mg < 256) ? values + (size_t)mg * 16 * 512
                                      : query + (size_t)(mg - 256) * 16 * 512;
        {
            const int row = tid >> 4, c0 = (tid & 15) * 4;
            #pragma unroll
            for (int i = 0; i < 8; ++i)
                *(float4*)&TA[row][c0 + i * 64] =
                    *(const float4*)&src[(size_t)row * 512 + c0 + i * 64];
        }
        __syncthreads();
        {
            const int ks = tid >> 4;
            const int l4 = (tid & 15) * 4;
            const size_t base = ((size_t)(mg * 16 + ks)) * 512;
            #pragma unroll
            for (int li = 0; li < 4; ++li) {
                const int lane = l4 + li;
                const int lr = lane & 15, lg = lane >> 4;
                bf16x8 hv, lv;
                #pragma unroll
                for (int j = 0; j < 8; ++j) {
                    short h, l;
                    f32_to_bf16_pair(TA[lr][ks * 32 + lg * 8 + j], h, l);
                    hv[j] = h; lv[j] = l;
                }
                *(bf16x8*)(AHi + base + lane * 8) = hv;
                *(bf16x8*)(ALo + base + lane * 8) = lv;
            }
        }
    }
}

// ---------------------------------------------------------------------------
// Kernel 1: MFMA split-bf16 GEMM (r12-validated, unchanged).
// ---------------------------------------------------------------------------
__global__ __launch_bounds__(128) void gemm_mfma(
    const short* __restrict__ AHi, const short* __restrict__ ALo,
    const short* __restrict__ BHi, const short* __restrict__ BLo,
    float* __restrict__ EwO, float* __restrict__ EuO)
{
    const int bid = blockIdx.x;
    const int mt = bid >> 2, nt = bid & 3;
    const int tid = threadIdx.x;
    const int w = tid >> 6, l = tid & 63;
    const int lr = l & 15, lg = l >> 4;

    float* C; int m0, mg, matoff;
    if (mt < 128) { C = EwO; m0 = mt * 32; mg = mt * 2 + w; matoff = 0; }
    else { C = EuO; m0 = (mt - 128) * 32; mg = 256 + (mt - 128) * 2 + w; matoff = 131072; }

    const short* ah_p = AHi + ((size_t)mg * 16) * 512 + l * 8;
    const short* al_p = ALo + ((size_t)mg * 16) * 512 + l * 8;
    const short* bh_p = BHi + matoff + ((size_t)(nt * 4) * 16) * 512 + l * 8;
    const short* bl_p = BLo + matoff + ((size_t)(nt * 4) * 16) * 512 + l * 8;

    f32x4 acc[4];
    #pragma unroll
    for (int nc = 0; nc < 4; ++nc) acc[nc] = (f32x4){0.f, 0.f, 0.f, 0.f};

    #pragma unroll 2
    for (int ks = 0; ks < 16; ++ks) {
        bf16x8 ah = *(const bf16x8*)(ah_p + (size_t)ks * 512);
        bf16x8 al = *(const bf16x8*)(al_p + (size_t)ks * 512);
        #pragma unroll
        for (int nc = 0; nc < 4; ++nc) {
            bf16x8 bh = *(const bf16x8*)(bh_p + ((size_t)(nc * 16 + ks)) * 512);
            bf16x8 bl = *(const bf16x8*)(bl_p + ((size_t)(nc * 16 + ks)) * 512);
            acc[nc] = __builtin_amdgcn_mfma_f32_16x16x32_bf16(ah, bh, acc[nc], 0, 0, 0);
            acc[nc] = __builtin_amdgcn_mfma_f32_16x16x32_bf16(al, bh, acc[nc], 0, 0, 0);
            acc[nc] = __builtin_amdgcn_mfma_f32_16x16x32_bf16(ah, bl, acc[nc], 0, 0, 0);
        }
    }

    const float SCL = 2.8853900817779268f;  // 2*log2(e)
    float* cp = C + (size_t)(m0 + w * 16 + lg * 4) * 256 + nt * 64 + lr;
    #pragma unroll
    for (int nc = 0; nc < 4; ++nc)
        #pragma unroll
        for (int r = 0; r < 4; ++r)
            cp[(size_t)r * 256 + nc * 16] = __builtin_amdgcn_exp2f(acc[nc][r] * SCL);
}

// ---------------------------------------------------------------------------
// Kernel 2: score partials, 2t x 4s micro-tile, 4-way a-split (r15-validated).
// Grid 1024 = 8b x 4ah x 4tt x 8st, 256 thr.  Block = 32t x 64s x 64a.
// S = sum_a V[a] * rcp(fmaf(Ew, Eu, 1)).
// ---------------------------------------------------------------------------
__global__ __launch_bounds__(256) void scores_k(
    const float* __restrict__ Ew, const float* __restrict__ Eu,
    const float* __restrict__ Va, float* __restrict__ scoresP)
{
    __shared__ float Ws[64][68];
    __shared__ float Us[32][68];

    const int bid = blockIdx.x;
    const int b = bid & 7;               // XCD-pinned per batch
    const int rest = bid >> 3;           // 0..127
    const int ah = rest & 3;
    const int tt = (rest >> 2) & 3;      // 4 t-tiles of 32
    const int st = rest >> 4;            // 8 s-tiles of 64
    const int t0 = tt * 32, s0 = st * 64, a0 = ah * 64;
    const int tid = threadIdx.x;

    {   // stage Ew (64s x 64a) and Eu (32t x 64a)
        const int r = tid >> 2, c16 = (tid & 3) * 16;
        const float* wsrc = Ew + (size_t)(b * 512 + s0 + r) * 256 + a0 + c16;
        #pragma unroll
        for (int q = 0; q < 4; ++q)
            *(float4*)&Ws[r][c16 + q * 4] = *(const float4*)&wsrc[q * 4];
        const int r8 = tid >> 3, c8 = (tid & 7) * 8;
        const float* usrc = Eu + (size_t)(b * 128 + t0 + r8) * 256 + a0 + c8;
        *(float4*)&Us[r8][c8]     = *(const float4*)&usrc[0];
        *(float4*)&Us[r8][c8 + 4] = *(const float4*)&usrc[4];
    }
    __syncthreads();

    const int tb = tid >> 4;             // t rows {tb, tb+16}
    const int ss = tid & 15;             // s rows {ss, ss+16, ss+32, ss+48}
    const float* Vp = Va + a0;

    float acc[2][4] = {};
    #pragma unroll 2
    for (int a = 0; a < 64; a += 4) {
        float4 u0 = *(const float4*)&Us[tb][a];
        float4 u1 = *(const float4*)&Us[tb + 16][a];
        float4 w0 = *(const float4*)&Ws[ss][a];
        float4 w1 = *(const float4*)&Ws[ss + 16][a];
        float4 w2 = *(const float4*)&Ws[ss + 32][a];
        float4 w3 = *(const float4*)&Ws[ss + 48][a];
        const float uv[2][4] = {{u0.x, u0.y, u0.z, u0.w}, {u1.x, u1.y, u1.z, u1.w}};
        const float wv[4][4] = {{w0.x, w0.y, w0.z, w0.w}, {w1.x, w1.y, w1.z, w1.w},
                                {w2.x, w2.y, w2.z, w2.w}, {w3.x, w3.y, w3.z, w3.w}};
        #pragma unroll
        for (int q = 0; q < 4; ++q) {
            const float vq = Vp[a + q];  // wave-uniform -> scalar load
            #pragma unroll
            for (int i = 0; i < 2; ++i)
                #pragma unroll
                for (int k = 0; k < 4; ++k) {
                    float rc = __builtin_amdgcn_rcpf(fmaf(wv[k][q], uv[i][q], 1.f));
                    acc[i][k] = fmaf(vq, rc, acc[i][k]);
                }
        }
    }

    float* sp = scoresP + (size_t)ah * 524288
              + (size_t)(b * 128 + t0 + tb) * 512 + s0 + ss;
    #pragma unroll
    for (int k = 0; k < 4; ++k) sp[k * 16] = acc[0][k];
    sp += (size_t)16 * 512;
    #pragma unroll
    for (int k = 0; k < 4; ++k) sp[k * 16] = acc[1][k];
}

// ---------------------------------------------------------------------------
// Kernel 3: combine partials + softmax + context, 8t blocks, e-split 8.
// Grid 1024 = 8b x 16 tg(8t) x 8 eh, 256 thr.  p = softmax(-2*S).
// Ctx: s-split 8 (32 lanes each), 64-wide e-slice, float2 loads.
// LDS 30KB -> 5 blocks/CU capable; grid 4/CU.
// ---------------------------------------------------------------------------
__global__ __launch_bounds__(256) void softctx(
    const float* __restrict__ scoresP, const float* __restrict__ values,
    float* __restrict__ out_c, float* __restrict__ out_e)
{
    __shared__ float Ps[8][512];
    __shared__ float Part[7][8][64];

    const int bid = blockIdx.x;
    const int b = bid & 7;
    const int rest = bid >> 3;         // 0..127
    const int tg = rest & 15;
    const int eh = rest >> 4;          // 0..7
    const int t0 = tg * 8;
    const int tid = threadIdx.x;

    {   // softmax: row = tid>>5 (0..7), 32 lanes per row
        const int row = tid >> 5, lane = tid & 31;
        const float* sp = scoresP + (size_t)(b * 128 + t0 + row) * 512;
        float e[16]; float ssum = 0.f;
        #pragma unroll
        for (int k = 0; k < 16; ++k) {
            const int idx = k * 32 + lane;
            float s = sp[idx] + sp[524288 + idx] + sp[1048576 + idx] + sp[1572864 + idx];
            e[k] = __builtin_amdgcn_exp2f(s * -2.8853900817779268f);  // exp(-2S)
            ssum += e[k];
        }
        #pragma unroll
        for (int off = 16; off > 0; off >>= 1)      // stays within 32-lane group
            ssum += __shfl_xor(ssum, off);
        const float inv = 1.0f / ssum;
        float* erow = out_e + (size_t)(b * 128 + t0 + row) * 512;
        #pragma unroll
        for (int k = 0; k < 16; ++k) {
            float p = e[k] * inv;
            Ps[row][k * 32 + lane] = p;
            if (eh == 0) erow[k * 32 + lane] = p;
        }
    }
    __syncthreads();

    const int sh = tid >> 5;           // 0..7 s-split
    const int el = (tid & 31) * 2;     // 0..62
    const int e2 = eh * 64 + el;       // global e
    const int sb = sh * 64;
    const float* vb = values + (size_t)b * 262144;

    float2 a[8];
    #pragma unroll
    for (int r = 0; r < 8; ++r) a[r] = (float2){0.f, 0.f};

    #pragma unroll 2
    for (int s2 = 0; s2 < 64; s2 += 4) {
        float4 q[8];
        #pragma unroll
        for (int r = 0; r < 8; ++r)
            q[r] = *(const float4*)&Ps[r][sb + s2];
        #pragma unroll
        for (int j = 0; j < 4; ++j) {
            float2 v2 = *(const float2*)&vb[(size_t)(sb + s2 + j) * 512 + e2];
            #pragma unroll
            for (int r = 0; r < 8; ++r) {
                const float qv = (j == 0) ? q[r].x : (j == 1) ? q[r].y
                               : (j == 2) ? q[r].z : q[r].w;
                a[r].x = fmaf(qv, v2.x, a[r].x);
                a[r].y = fmaf(qv, v2.y, a[r].y);
            }
        }
    }

    if (sh) {
        #pragma unroll
        for (int r = 0; r < 8; ++r)
            *(float2*)&Part[sh - 1][r][el] = a[r];
    }
    __syncthreads();
    if (!sh) {
        #pragma unroll
        for (int r = 0; r < 8; ++r) {
            float2 accv = a[r];
            #pragma unroll
            for (int g = 0; g < 7; ++g) {
                float2 p2 = *(const float2*)&Part[g][r][el];
                accv.x += p2.x; accv.y += p2.y;
            }
            *(float2*)&out_c[(size_t)(b * 128 + t0 + r) * 512 + e2] = accv;
        }
    }
}

// ---------------------------------------------------------------------------
extern "C" void kernel_launch(void* const* d_in, const int* in_sizes, int n_in,
                              void* d_out, int out_size, void* d_ws, size_t ws_size,
                              hipStream_t stream) {
    const float* values = (const float*)d_in[0];  // [8,512,512]
    const float* query  = (const float*)d_in[1];  // [8,128,512]
    const float* W_h    = (const float*)d_in[2];  // [512,256]
    const float* U_a    = (const float*)d_in[3];  // [512,256]
    const float* V_a    = (const float*)d_in[4];  // [1,256]

    float* ws      = (float*)d_ws;
    float* Ew      = ws;                           // 4096*256 f32
    float* Eu      = ws + 1048576;                 // 1024*256 f32
    float* scoresP = ws + 1310720;                 // 4 * 524288 f32
    short* S       = (short*)(ws + 3407872);
    short* AHi     = S;                            // 5120*512 bf16
    short* ALo     = S + 2621440;
    short* BHi     = S + 5242880;                  // 2*256*512 bf16
    short* BLo     = S + 5505024;

    float* out_c = (float*)d_out;                  // [8,128,512]
    float* out_e = out_c + 8 * 128 * 512;          // [8,128,512]

    hipLaunchKernelGGL(prep, dim3(384), dim3(256), 0, stream,
                       W_h, U_a, values, query, BHi, BLo, AHi, ALo);
    hipLaunchKernelGGL(gemm_mfma, dim3(640), dim3(128), 0, stream,
                       AHi, ALo, BHi, BLo, Ew, Eu);
    hipLaunchKernelGGL(scores_k, dim3(1024), dim3(256), 0, stream,
                       Ew, Eu, V_a, scoresP);
    hipLaunchKernelGGL(softctx, dim3(1024), dim3(256), 0, stream,
                       scoresP, values, out_c, out_e);
}

// Round 18
// 52.735 us; speedup vs baseline: 1.0803x; 1.0375x over previous
//
#include <hip/hip_runtime.h>
#include <hip/hip_bf16.h>

// B=8, Te=512, Td=128, D_ENC=D_DEC=512, ATT=256
// BEST-MEASURED CONFIG (round-14 submission, 52.74us) restored verbatim:
//  prep      : A,B -> fragment-swizzled bf16 hi/lo planes
//  gemm_mfma : split-bf16 3-pass MFMA; epilogue stores Ew/Eu = exp2(2log2e*x)
//  scores_k  : S = sum_a V[a]*rcp(fmaf(Ew,Eu,1)), 2t x 4s micro-tile, 4-way a-split
//  softctx   : p = softmax(-2S); context + out_e  (8t blocks, e-split 4)

typedef __attribute__((ext_vector_type(8))) short bf16x8;
typedef __attribute__((ext_vector_type(4))) float f32x4;

__device__ inline void f32_to_bf16_pair(float x, short& h, short& l) {
    unsigned u = __builtin_bit_cast(unsigned, x);
    unsigned r = u + 0x7FFFu + ((u >> 16) & 1u);           // RNE
    h = (short)(r >> 16);
    float xh = __builtin_bit_cast(float, r & 0xFFFF0000u);
    float xl = x - xh;
    unsigned u2 = __builtin_bit_cast(unsigned, xl);
    unsigned r2 = u2 + 0x7FFFu + ((u2 >> 16) & 1u);
    l = (short)(r2 >> 16);
}

// ---------------------------------------------------------------------------
// Kernel 0: merged prep (r12-validated).
// ---------------------------------------------------------------------------
__global__ __launch_bounds__(256) void prep(
    const float* __restrict__ W_h, const float* __restrict__ U_a,
    const float* __restrict__ values, const float* __restrict__ query,
    short* __restrict__ BHi, short* __restrict__ BLo,
    short* __restrict__ AHi, short* __restrict__ ALo)
{
    __shared__ float TW[64][65];
    __shared__ float TA[16][516];
    const int bid = blockIdx.x;
    const int tid = threadIdx.x;

    if (bid < 64) {
        const int mat = bid >> 5, nb = (bid >> 3) & 3, kb = bid & 7;
        const float* W = mat ? U_a : W_h;
        {
            const int krow = tid >> 2, cq = (tid & 3) * 16;
            const float* src = W + (size_t)(kb * 64 + krow) * 256 + nb * 64 + cq;
            #pragma unroll
            for (int q = 0; q < 4; ++q)
                *(float4*)&TW[krow][cq + q * 4] = *(const float4*)&src[q * 4];
        }
        __syncthreads();
        {
            const int f = tid >> 5;
            const int ngl = f >> 1, ksl = f & 1;
            const int l0 = (tid & 31) * 2;
            const int ngrp = nb * 4 + ngl;
            const int ksg = kb * 2 + ksl;
            const size_t base = (size_t)mat * 131072 + (size_t)(ngrp * 16 + ksg) * 512;
            #pragma unroll
            for (int li = 0; li < 2; ++li) {
                const int lane = l0 + li;
                const int lr = lane & 15, lg = lane >> 4;
                bf16x8 hv, lv;
                #pragma unroll
                for (int j = 0; j < 8; ++j) {
                    short h, l;
                    f32_to_bf16_pair(TW[ksl * 32 + lg * 8 + j][ngl * 16 + lr], h, l);
                    hv[j] = h; lv[j] = l;
                }
                *(bf16x8*)(BHi + base + lane * 8) = hv;
                *(bf16x8*)(BLo + base + lane * 8) = lv;
            }
        }
    } else {
        const int mg = bid - 64;
        const float* src = (mg < 256) ? values + (size_t)mg * 16 * 512
                                      : query + (size_t)(mg - 256) * 16 * 512;
        {
            const int row = tid >> 4, c0 = (tid & 15) * 4;
            #pragma unroll
            for (int i = 0; i < 8; ++i)
                *(float4*)&TA[row][c0 + i * 64] =
                    *(const float4*)&src[(size_t)row * 512 + c0 + i * 64];
        }
        __syncthreads();
        {
            const int ks = tid >> 4;
            const int l4 = (tid & 15) * 4;
            const size_t base = ((size_t)(mg * 16 + ks)) * 512;
            #pragma unroll
            for (int li = 0; li < 4; ++li) {
                const int lane = l4 + li;
                const int lr = lane & 15, lg = lane >> 4;
                bf16x8 hv, lv;
                #pragma unroll
                for (int j = 0; j < 8; ++j) {
                    short h, l;
                    f32_to_bf16_pair(TA[lr][ks * 32 + lg * 8 + j], h, l);
                    hv[j] = h; lv[j] = l;
                }
                *(bf16x8*)(AHi + base + lane * 8) = hv;
                *(bf16x8*)(ALo + base + lane * 8) = lv;
            }
        }
    }
}

// ---------------------------------------------------------------------------
// Kernel 1: MFMA split-bf16 GEMM (r12-validated).
// ---------------------------------------------------------------------------
__global__ __launch_bounds__(128) void gemm_mfma(
    const short* __restrict__ AHi, const short* __restrict__ ALo,
    const short* __restrict__ BHi, const short* __restrict__ BLo,
    float* __restrict__ EwO, float* __restrict__ EuO)
{
    const int bid = blockIdx.x;
    const int mt = bid >> 2, nt = bid & 3;
    const int tid = threadIdx.x;
    const int w = tid >> 6, l = tid & 63;
    const int lr = l & 15, lg = l >> 4;

    float* C; int m0, mg, matoff;
    if (mt < 128) { C = EwO; m0 = mt * 32; mg = mt * 2 + w; matoff = 0; }
    else { C = EuO; m0 = (mt - 128) * 32; mg = 256 + (mt - 128) * 2 + w; matoff = 131072; }

    const short* ah_p = AHi + ((size_t)mg * 16) * 512 + l * 8;
    const short* al_p = ALo + ((size_t)mg * 16) * 512 + l * 8;
    const short* bh_p = BHi + matoff + ((size_t)(nt * 4) * 16) * 512 + l * 8;
    const short* bl_p = BLo + matoff + ((size_t)(nt * 4) * 16) * 512 + l * 8;

    f32x4 acc[4];
    #pragma unroll
    for (int nc = 0; nc < 4; ++nc) acc[nc] = (f32x4){0.f, 0.f, 0.f, 0.f};

    #pragma unroll 2
    for (int ks = 0; ks < 16; ++ks) {
        bf16x8 ah = *(const bf16x8*)(ah_p + (size_t)ks * 512);
        bf16x8 al = *(const bf16x8*)(al_p + (size_t)ks * 512);
        #pragma unroll
        for (int nc = 0; nc < 4; ++nc) {
            bf16x8 bh = *(const bf16x8*)(bh_p + ((size_t)(nc * 16 + ks)) * 512);
            bf16x8 bl = *(const bf16x8*)(bl_p + ((size_t)(nc * 16 + ks)) * 512);
            acc[nc] = __builtin_amdgcn_mfma_f32_16x16x32_bf16(ah, bh, acc[nc], 0, 0, 0);
            acc[nc] = __builtin_amdgcn_mfma_f32_16x16x32_bf16(al, bh, acc[nc], 0, 0, 0);
            acc[nc] = __builtin_amdgcn_mfma_f32_16x16x32_bf16(ah, bl, acc[nc], 0, 0, 0);
        }
    }

    const float SCL = 2.8853900817779268f;  // 2*log2(e)
    float* cp = C + (size_t)(m0 + w * 16 + lg * 4) * 256 + nt * 64 + lr;
    #pragma unroll
    for (int nc = 0; nc < 4; ++nc)
        #pragma unroll
        for (int r = 0; r < 4; ++r)
            cp[(size_t)r * 256 + nc * 16] = __builtin_amdgcn_exp2f(acc[nc][r] * SCL);
}

// ---------------------------------------------------------------------------
// Kernel 2: score partials, 2t x 4s micro-tile, 4-way a-split.
// Grid 1024 = 8b x 4ah x 4tt x 8st, 256 thr.  Block = 32t x 64s x 64a.
// S = sum_a V[a] * rcp(fmaf(Ew, Eu, 1)).
// ---------------------------------------------------------------------------
__global__ __launch_bounds__(256) void scores_k(
    const float* __restrict__ Ew, const float* __restrict__ Eu,
    const float* __restrict__ Va, float* __restrict__ scoresP)
{
    __shared__ float Ws[64][68];
    __shared__ float Us[32][68];

    const int bid = blockIdx.x;
    const int b = bid & 7;               // XCD-pinned per batch
    const int rest = bid >> 3;           // 0..127
    const int ah = rest & 3;
    const int tt = (rest >> 2) & 3;      // 4 t-tiles of 32
    const int st = rest >> 4;            // 8 s-tiles of 64
    const int t0 = tt * 32, s0 = st * 64, a0 = ah * 64;
    const int tid = threadIdx.x;

    {   // stage Ew (64s x 64a) and Eu (32t x 64a)
        const int r = tid >> 2, c16 = (tid & 3) * 16;
        const float* wsrc = Ew + (size_t)(b * 512 + s0 + r) * 256 + a0 + c16;
        #pragma unroll
        for (int q = 0; q < 4; ++q)
            *(float4*)&Ws[r][c16 + q * 4] = *(const float4*)&wsrc[q * 4];
        const int r8 = tid >> 3, c8 = (tid & 7) * 8;
        const float* usrc = Eu + (size_t)(b * 128 + t0 + r8) * 256 + a0 + c8;
        *(float4*)&Us[r8][c8]     = *(const float4*)&usrc[0];
        *(float4*)&Us[r8][c8 + 4] = *(const float4*)&usrc[4];
    }
    __syncthreads();

    const int tb = tid >> 4;             // t rows {tb, tb+16}
    const int ss = tid & 15;             // s rows {ss, ss+16, ss+32, ss+48}
    const float* Vp = Va + a0;

    float acc[2][4] = {};
    #pragma unroll 2
    for (int a = 0; a < 64; a += 4) {
        float4 u0 = *(const float4*)&Us[tb][a];
        float4 u1 = *(const float4*)&Us[tb + 16][a];
        float4 w0 = *(const float4*)&Ws[ss][a];
        float4 w1 = *(const float4*)&Ws[ss + 16][a];
        float4 w2 = *(const float4*)&Ws[ss + 32][a];
        float4 w3 = *(const float4*)&Ws[ss + 48][a];
        const float uv[2][4] = {{u0.x, u0.y, u0.z, u0.w}, {u1.x, u1.y, u1.z, u1.w}};
        const float wv[4][4] = {{w0.x, w0.y, w0.z, w0.w}, {w1.x, w1.y, w1.z, w1.w},
                                {w2.x, w2.y, w2.z, w2.w}, {w3.x, w3.y, w3.z, w3.w}};
        #pragma unroll
        for (int q = 0; q < 4; ++q) {
            const float vq = Vp[a + q];  // wave-uniform -> scalar load
            #pragma unroll
            for (int i = 0; i < 2; ++i)
                #pragma unroll
                for (int k = 0; k < 4; ++k) {
                    float rc = __builtin_amdgcn_rcpf(fmaf(wv[k][q], uv[i][q], 1.f));
                    acc[i][k] = fmaf(vq, rc, acc[i][k]);
                }
        }
    }

    float* sp = scoresP + (size_t)ah * 524288
              + (size_t)(b * 128 + t0 + tb) * 512 + s0 + ss;
    #pragma unroll
    for (int k = 0; k < 4; ++k) sp[k * 16] = acc[0][k];
    sp += (size_t)16 * 512;
    #pragma unroll
    for (int k = 0; k < 4; ++k) sp[k * 16] = acc[1][k];
}

// ---------------------------------------------------------------------------
// Kernel 3: combine partials + softmax + context, 8t per block, e-split 4.
// Grid 512 = 8b x 16 tg(8t) x 4 eh, 256 thr.  p = softmax(-2*S).
// ---------------------------------------------------------------------------
__global__ __launch_bounds__(256) void softctx(
    const float* __restrict__ scoresP, const float* __restrict__ values,
    float* __restrict__ out_c, float* __restrict__ out_e)
{
    __shared__ float Ps[8][512];
    __shared__ float Part[7][8][128];

    const int bid = blockIdx.x;
    const int b = bid & 7;
    const int rest = bid >> 3;         // 0..63
    const int tg = rest & 15;
    const int eh = rest >> 4;          // 0..3
    const int t0 = tg * 8;
    const int tid = threadIdx.x;

    {   // softmax: row = tid>>5 (0..7), 32 lanes per row
        const int row = tid >> 5, lane = tid & 31;
        const float* sp = scoresP + (size_t)(b * 128 + t0 + row) * 512;
        float e[16]; float ssum = 0.f;
        #pragma unroll
        for (int k = 0; k < 16; ++k) {
            const int idx = k * 32 + lane;
            float s = sp[idx] + sp[524288 + idx] + sp[1048576 + idx] + sp[1572864 + idx];
            e[k] = __builtin_amdgcn_exp2f(s * -2.8853900817779268f);  // exp(-2S)
            ssum += e[k];
        }
        #pragma unroll
        for (int off = 16; off > 0; off >>= 1)      // stays within 32-lane group
            ssum += __shfl_xor(ssum, off);
        const float inv = 1.0f / ssum;
        float* erow = out_e + (size_t)(b * 128 + t0 + row) * 512;
        #pragma unroll
        for (int k = 0; k < 16; ++k) {
            float p = e[k] * inv;
            Ps[row][k * 32 + lane] = p;
            if (eh == 0) erow[k * 32 + lane] = p;
        }
    }
    __syncthreads();

    const int sh = tid >> 5;           // 0..7 s-split
    const int el = (tid & 31) * 4;     // 0..124
    const int e4 = eh * 128 + el;
    const int sb = sh * 64;
    const float* vb = values + (size_t)b * 262144;

    f32x4 a[8];
    #pragma unroll
    for (int r = 0; r < 8; ++r) a[r] = (f32x4){0.f, 0.f, 0.f, 0.f};

    #pragma unroll 2
    for (int s2 = 0; s2 < 64; s2 += 4) {
        float4 q[8];
        #pragma unroll
        for (int r = 0; r < 8; ++r)
            q[r] = *(const float4*)&Ps[r][sb + s2];
        #pragma unroll
        for (int j = 0; j < 4; ++j) {
            float4 v4 = *(const float4*)&vb[(size_t)(sb + s2 + j) * 512 + e4];
            #pragma unroll
            for (int r = 0; r < 8; ++r) {
                const float qv = (j == 0) ? q[r].x : (j == 1) ? q[r].y
                               : (j == 2) ? q[r].z : q[r].w;
                a[r][0] = fmaf(qv, v4.x, a[r][0]);
                a[r][1] = fmaf(qv, v4.y, a[r][1]);
                a[r][2] = fmaf(qv, v4.z, a[r][2]);
                a[r][3] = fmaf(qv, v4.w, a[r][3]);
            }
        }
    }

    if (sh) {
        #pragma unroll
        for (int r = 0; r < 8; ++r)
            *(f32x4*)&Part[sh - 1][r][el] = a[r];
    }
    __syncthreads();
    if (!sh) {
        #pragma unroll
        for (int r = 0; r < 8; ++r) {
            f32x4 accv = a[r];
            #pragma unroll
            for (int g = 0; g < 7; ++g) {
                float4 p4 = *(const float4*)&Part[g][r][el];
                accv[0] += p4.x; accv[1] += p4.y; accv[2] += p4.z; accv[3] += p4.w;
            }
            *(f32x4*)&out_c[(size_t)(b * 128 + t0 + r) * 512 + e4] = accv;
        }
    }
}

// ---------------------------------------------------------------------------
extern "C" void kernel_launch(void* const* d_in, const int* in_sizes, int n_in,
                              void* d_out, int out_size, void* d_ws, size_t ws_size,
                              hipStream_t stream) {
    const float* values = (const float*)d_in[0];  // [8,512,512]
    const float* query  = (const float*)d_in[1];  // [8,128,512]
    const float* W_h    = (const float*)d_in[2];  // [512,256]
    const float* U_a    = (const float*)d_in[3];  // [512,256]
    const float* V_a    = (const float*)d_in[4];  // [1,256]

    float* ws      = (float*)d_ws;
    float* Ew      = ws;                           // 4096*256 f32
    float* Eu      = ws + 1048576;                 // 1024*256 f32
    float* scoresP = ws + 1310720;                 // 4 * 524288 f32
    short* S       = (short*)(ws + 3407872);
    short* AHi     = S;                            // 5120*512 bf16
    short* ALo     = S + 2621440;
    short* BHi     = S + 5242880;                  // 2*256*512 bf16
    short* BLo     = S + 5505024;

    float* out_c = (float*)d_out;                  // [8,128,512]
    float* out_e = out_c + 8 * 128 * 512;          // [8,128,512]

    hipLaunchKernelGGL(prep, dim3(384), dim3(256), 0, stream,
                       W_h, U_a, values, query, BHi, BLo, AHi, ALo);
    hipLaunchKernelGGL(gemm_mfma, dim3(640), dim3(128), 0, stream,
                       AHi, ALo, BHi, BLo, Ew, Eu);
    hipLaunchKernelGGL(scores_k, dim3(1024), dim3(256), 0, stream,
                       Ew, Eu, V_a, scoresP);
    hipLaunchKernelGGL(softctx, dim3(512), dim3(256), 0, stream,
                       scoresP, values, out_c, out_e);
}